// Round 14
// baseline (90.354 us; speedup 1.0000x reference)
//
#include <hip/hip_runtime.h>
#include <hip/hip_bf16.h>

#define BB 64
#define TT 32768
#define KK 256
#define LL 2065          // conv out length
#define LT 64            // k1 l-values per block
#define NLT 33           // ceil(LL/LT)
#define NPART (BB*NLT)   // 2112 partial slots per channel
#define NJ 19            // j-range for synthesis (P4 packing)
#define NPT3 16          // k3 P-tiles per batch (32 packed positions each)
#define HBP 264          // k1 hb row stride in ushorts (528 B)

typedef __attribute__((ext_vector_type(8))) short short8;
typedef __attribute__((ext_vector_type(4))) float f32x4;
typedef __attribute__((ext_vector_type(4))) int int4v;

__device__ __forceinline__ unsigned short f2bf(float f) {
    unsigned u = __builtin_bit_cast(unsigned, f);
    unsigned r = (u + 0x7FFFu + ((u >> 16) & 1u)) >> 16;
    return (unsigned short)r;
}
// packed f32x2 -> bf16x2 (RNE), single instruction
__device__ __forceinline__ unsigned pkbf(float a, float b) {
    unsigned r;
    asm("v_cvt_pk_bf16_f32 %0, %1, %2" : "=v"(r) : "v"(a), "v"(b));
    return r;
}
__device__ __forceinline__ float bf2f(unsigned short v) {
    return __builtin_bit_cast(float, (unsigned)v << 16);
}
// async global->LDS, 16B per lane
__device__ __forceinline__ void gload_lds16(const void* g, void* l) {
    __builtin_amdgcn_global_load_lds(
        (const __attribute__((address_space(1))) unsigned int*)g,
        (__attribute__((address_space(3))) unsigned int*)l, 16, 0, 0);
}

// ---------------- k0s: sparse gated-Haar weight table Wp[9][32][8] + cbs ----------------
// level t, lane-group g, tap i: global tap j = 8g+i, row o = o(t,g,i); value = cs*cw*(cgt+1)/2.
// Haar support: o in [2^t,2^(t+1)) has support 256/2^t starting (o-2^t)*256/2^t; cw=0 outside.
__global__ void k0s_wp(const float* __restrict__ cw, const float* __restrict__ cgt,
                       const float* __restrict__ cs, const float* __restrict__ cb,
                       float* __restrict__ Wp, float* __restrict__ cbs)
{
    int idx = blockIdx.x*256 + threadIdx.x;    // 2304 = 9*256
    int t = idx >> 8, gi = idx & 255;
    int g = gi >> 3, i = gi & 7;
    int o;
    switch (t) {
        case 0: o = 0; break;
        case 1: o = 1; break;
        case 2: o = 2 + (g>>4); break;
        case 3: o = 4 + (g>>3); break;
        case 4: o = 8 + (g>>2); break;
        case 5: o = 16 + (g>>1); break;
        case 6: o = 32 + g; break;
        case 7: o = 64 + 2*g + (i>>2); break;
        default: o = 128 + 4*g + (i>>1); break;
    }
    int j = 8*g + i;
    Wp[idx] = cs[o] * cw[o*KK + j] * (cgt[o*KK + j] + 1.0f) * 0.5f;
    if (blockIdx.x == 0) cbs[threadIdx.x] = cs[threadIdx.x]*cb[threadIdx.x];
}

// ---------------- k1: sparse-Haar analysis conv (fp32 VALU) + relu + bf16 h + BN partials
// 256 thr = 4 waves; wave covers 16 l-columns (2 per iter via 32-lane halves).
// Lane group g owns taps 8g..8g+7; levels 0-5 reduced via shfl_xor butterfly.
__global__ __launch_bounds__(256, 3)
void k1_conv(const float* __restrict__ x, const float* __restrict__ cbs,
             const float* __restrict__ Wp,
             unsigned short* __restrict__ hout,
             float* __restrict__ psum, float* __restrict__ psq)
{
    __shared__ __align__(16) float xs[1280];              // x window fp32 (5120 B)
    __shared__ __align__(16) unsigned short hb[64*HBP];   // h tile bf16 (33792 B)

    const int tid   = threadIdx.x;
    const int ltile = blockIdx.x;
    const int b     = blockIdx.y;
    const int l0    = ltile * LT;
    const int lane  = tid & 63;
    const int wv    = tid >> 6;
    const int hf    = lane >> 5;   // column half
    const int g     = lane & 31;

    // stage x window (zero-padded both ends)
    {
        const float* xb = x + (size_t)b*TT;
        const long base = (long)l0*16 - 256;
        #pragma unroll
        for (int i = 0; i < 5; ++i) {
            int t = tid + i*256;
            long p = base + t;
            xs[t] = (p >= 0 && p < TT) ? xb[p] : 0.0f;
        }
    }

    // per-lane sparse weights (72 VGPRs) + bias constants
    float w[9][8];
    #pragma unroll
    for (int t = 0; t < 9; ++t) {
        const f32x4* src = (const f32x4*)(Wp + (t*32 + g)*8);
        f32x4 a = src[0], bq = src[1];
        w[t][0]=a[0]; w[t][1]=a[1]; w[t][2]=a[2]; w[t][3]=a[3];
        w[t][4]=bq[0]; w[t][5]=bq[1]; w[t][6]=bq[2]; w[t][7]=bq[3];
    }
    f32x4 cb8 = *(const f32x4*)&cbs[128 + 4*g];
    float cb7a = cbs[64 + 2*g], cb7b = cbs[65 + 2*g];
    float cb6 = cbs[32 + g];
    float cb5 = cbs[16 + (g>>1)];
    float cb4 = cbs[8 + (g>>2)];
    float cb3 = cbs[4 + (g>>3)];
    float cb2 = cbs[2 + (g>>4)];
    float cb1 = cbs[1], cb0 = cbs[0];
    __syncthreads();

    #pragma unroll 1
    for (int it = 0; it < 8; ++it) {
        const int lrow = wv*16 + it*2 + hf;
        float xr[8];
        {
            const f32x4* xp = (const f32x4*)&xs[16*lrow + 8*g];
            f32x4 x0 = xp[0], x1 = xp[1];
            xr[0]=x0[0]; xr[1]=x0[1]; xr[2]=x0[2]; xr[3]=x0[3];
            xr[4]=x1[0]; xr[5]=x1[1]; xr[6]=x1[2]; xr[7]=x1[3];
        }
        // level 8: 4 local channels (2 taps each)
        float v8[4];
        #pragma unroll
        for (int u = 0; u < 4; ++u)
            v8[u] = fmaf(w[8][2*u+1], xr[2*u+1], w[8][2*u]*xr[2*u]);
        // level 7: 2 local channels (4 taps)
        float v7a = w[7][0]*xr[0], v7b = w[7][4]*xr[4];
        #pragma unroll
        for (int i = 1; i < 4; ++i) {
            v7a = fmaf(w[7][i], xr[i], v7a);
            v7b = fmaf(w[7][4+i], xr[4+i], v7b);
        }
        // levels 0..6: 8-tap partials
        float p[7];
        #pragma unroll
        for (int t = 0; t < 7; ++t) {
            float acc = w[t][0]*xr[0];
            #pragma unroll
            for (int i = 1; i < 8; ++i) acc = fmaf(w[t][i], xr[i], acc);
            p[t] = acc;
        }
        // butterflies (within 32-lane halves)
        p[5] += __shfl_xor(p[5], 1);
        p[4] += __shfl_xor(p[4], 1); p[4] += __shfl_xor(p[4], 2);
        p[3] += __shfl_xor(p[3], 1); p[3] += __shfl_xor(p[3], 2); p[3] += __shfl_xor(p[3], 4);
        p[2] += __shfl_xor(p[2], 1); p[2] += __shfl_xor(p[2], 2); p[2] += __shfl_xor(p[2], 4);
        p[2] += __shfl_xor(p[2], 8);
        p[1] += __shfl_xor(p[1], 1); p[1] += __shfl_xor(p[1], 2); p[1] += __shfl_xor(p[1], 4);
        p[1] += __shfl_xor(p[1], 8); p[1] += __shfl_xor(p[1], 16);
        p[0] += __shfl_xor(p[0], 1); p[0] += __shfl_xor(p[0], 2); p[0] += __shfl_xor(p[0], 4);
        p[0] += __shfl_xor(p[0], 8); p[0] += __shfl_xor(p[0], 16);

        unsigned short* hr = hb + lrow*HBP;
        // L8: channels 128+4g..131+4g (b64 write)
        {
            float h0 = fmaxf(v8[0] + cb8[0], 0.f), h1 = fmaxf(v8[1] + cb8[1], 0.f);
            float h2 = fmaxf(v8[2] + cb8[2], 0.f), h3 = fmaxf(v8[3] + cb8[3], 0.f);
            unsigned u0 = pkbf(h0, h1), u1 = pkbf(h2, h3);
            *(unsigned long long*)(hr + 128 + 4*g) =
                (unsigned long long)u0 | ((unsigned long long)u1 << 32);
        }
        // L7: channels 64+2g (b32)
        {
            float h0 = fmaxf(v7a + cb7a, 0.f), h1 = fmaxf(v7b + cb7b, 0.f);
            *(unsigned*)(hr + 64 + 2*g) = pkbf(h0, h1);
        }
        // L6: channel 32+g
        {
            float h0 = fmaxf(p[6] + cb6, 0.f);
            hr[32 + g] = (unsigned short)(pkbf(h0, h0) & 0xffffu);
        }
        if ((g & 1) == 0) {
            float h0 = fmaxf(p[5] + cb5, 0.f);
            hr[16 + (g>>1)] = (unsigned short)(pkbf(h0, h0) & 0xffffu);
        }
        if ((g & 3) == 0) {
            float h0 = fmaxf(p[4] + cb4, 0.f);
            hr[8 + (g>>2)] = (unsigned short)(pkbf(h0, h0) & 0xffffu);
        }
        if ((g & 7) == 0) {
            float h0 = fmaxf(p[3] + cb3, 0.f);
            hr[4 + (g>>3)] = (unsigned short)(pkbf(h0, h0) & 0xffffu);
        }
        if ((g & 15) == 0) {
            float h0 = fmaxf(p[2] + cb2, 0.f);
            hr[2 + (g>>4)] = (unsigned short)(pkbf(h0, h0) & 0xffffu);
        }
        if (g == 0) {
            float h0 = fmaxf(p[0] + cb0, 0.f);
            float h1 = fmaxf(p[1] + cb1, 0.f);
            *(unsigned*)(hr + 0) = pkbf(h0, h1);
        }
    }
    __syncthreads();

    const int nval = (l0 + LT <= LL) ? LT : (LL - l0);

    // coalesced h writeback: 2048 16B-chunks, 8 per thread
    #pragma unroll
    for (int i = 0; i < 8; ++i) {
        int item = i*256 + tid;
        int row = item >> 5, chunk = item & 31;
        if (row < nval) {
            int4v v = *(const int4v*)(hb + row*HBP + chunk*8);
            *(int4v*)(hout + (((size_t)(b*LL + l0 + row)) << 8) + chunk*8) = v;
        }
    }
    // BN partials from bf16 tile: thread = channel
    {
        float s = 0.f, q = 0.f;
        for (int row = 0; row < nval; ++row) {
            float v = bf2f(hb[row*HBP + tid]);
            s += v; q = fmaf(v, v, q);
        }
        int slot = b*NLT + ltile;
        psum[tid*NPART + slot] = s;
        psq [tid*NPART + slot] = q;
    }
}

// ---------------- k2: BN stats -> folded synthesis weights W3s[k][c] + SWS ----------------
__global__ __launch_bounds__(256)
void k2_bn(const float* __restrict__ psum, const float* __restrict__ psq,
           const float* __restrict__ bng, const float* __restrict__ bnb,
           const float* __restrict__ ctw, const float* __restrict__ ctg,
           const float* __restrict__ ctscale,
           float* __restrict__ W3s, float* __restrict__ SWS)
{
    __shared__ double rs[4], rq[4];
    __shared__ float s_a, s_bc;
    __shared__ float swl[256];
    const int c = blockIdx.x;
    const int tid = threadIdx.x;
    double s = 0.0, q = 0.0;
    for (int i = tid; i < NPART; i += 256) {
        s += (double)psum[c*NPART + i];
        q += (double)psq [c*NPART + i];
    }
    for (int off = 32; off > 0; off >>= 1) {
        s += __shfl_down(s, off);
        q += __shfl_down(q, off);
    }
    if ((tid & 63) == 0) { rs[tid >> 6] = s; rq[tid >> 6] = q; }
    __syncthreads();
    if (tid == 0) {
        double st = rs[0]+rs[1]+rs[2]+rs[3];
        double qt = rq[0]+rq[1]+rq[2]+rq[3];
        const double cnt = (double)BB * (double)LL;
        double mu = st / cnt;
        double var = qt / cnt - mu*mu;
        float rsig = (float)(1.0 / sqrt(var + 1e-5));
        float a = bng[c] * rsig;
        s_a = a;
        s_bc = bnb[c] - (float)mu * a;
    }
    __syncthreads();
    float a = s_a, bc = s_bc, scl = ctscale[0];
    int gi = c*KK + tid;                          // k = tid
    float wt = ctw[gi] * (ctg[gi] + 1.0f) * 0.5f;
    W3s[tid*KK + c] = scl * a * wt;
    swl[tid] = wt * bc;
    __syncthreads();
    if (tid < 16) {
        float acc2 = 0.0f;
        #pragma unroll
        for (int d = 0; d < 16; ++d) acc2 += swl[d*16 + tid];
        SWS[c*16 + tid] = acc2;
    }
}

__global__ __launch_bounds__(256)
void k2b_const(const float* __restrict__ SWS, const float* __restrict__ ctb,
               const float* __restrict__ ctscale, float* __restrict__ C2)
{
    __shared__ float accb[16][17];
    int tid = threadIdx.x;
    int r = tid & 15, cc = tid >> 4;
    float s = 0.0f;
    #pragma unroll
    for (int i = 0; i < 16; ++i) s += SWS[(cc*16 + i)*16 + r];
    accb[cc][r] = s;
    __syncthreads();
    if (tid < 16) {
        float t = 0.0f;
        #pragma unroll
        for (int i = 0; i < 16; ++i) t += accb[i][tid];
        C2[tid] = ctscale[0] * (t + ctb[0]);
    }
}

// ---------------- k2c: B2f fragment table for synthesis ----------------
__global__ void k2c_b2f(const float* __restrict__ W3s, unsigned short* __restrict__ B2f)
{
    int idx = blockIdx.x*256 + threadIdx.x;        // 38912 threads
    int lane = idx & 63;
    int ntG  = (idx>>6) & 3;
    int kk   = (idx>>8) & 7;
    int j    = idx>>11;
    int c    = kk*32 + ((lane>>4)<<3);
    int r    = lane & 15;
    int d    = ntG + 15 - j;
    short8 v;
    if (d >= 0 && d <= 15) {
        const float* wr = W3s + (size_t)(16*d + r)*KK + c;
        #pragma unroll
        for (int i = 0; i < 8; ++i) v[i] = (short)f2bf(wr[i]);
    } else {
        #pragma unroll
        for (int i = 0; i < 8; ++i) v[i] = 0;
    }
    *(short8*)(B2f + (size_t)idx*8) = v;
}

// ---------------- k3: synthesis conv, 32-P tiles, j-partitioned, valid-nt only -------
__global__ __launch_bounds__(512, 4)
void k3_synth(const unsigned short* __restrict__ h, const unsigned short* __restrict__ B2f,
              const float* __restrict__ C2, float* __restrict__ out)
{
    __shared__ __align__(16) char As[144*512];    // 73728 B; red[8][32][68] aliases after
    const int tid  = threadIdx.x;
    const int lane = tid & 63;
    const int w    = tid >> 6;       // 0..7
    const int b    = blockIdx.y;
    const int P0   = blockIdx.x * 32;

    const char* hbase = (const char*)h + (((size_t)(b*LL) + 4*P0 + 1) << 9);

    {
        const int rl = lane >> 5;
        #pragma unroll
        for (int i = 0; i < 9; ++i) {
            int r0  = w*18 + i*2;
            int row = r0 + rl;
            int chunk = (lane & 31) ^ ((row >> 2) & 7);
            gload_lds16(hbase + (size_t)row*512 + chunk*16, As + r0*512);
        }
    }
    __syncthreads();

    const int li = lane & 15;
    const int gq = lane >> 4;

    f32x4 acc[2][4];
    #pragma unroll
    for (int mt = 0; mt < 2; ++mt)
        #pragma unroll
        for (int nt = 0; nt < 4; ++nt) acc[mt][nt] = (f32x4){0.f,0.f,0.f,0.f};

    #pragma unroll 1
    for (int jj = 0; jj < 3; ++jj) {
        const int j = w + jj*8;
        if (j >= NJ) break;
        short8 bfA[4], bfB[4];
        #pragma unroll
        for (int nt = 0; nt < 4; ++nt)
            if (nt >= j-15 && nt <= j)
                bfA[nt] = *(const short8*)(B2f + (((size_t)(j*8 + 0)*4 + nt)*64 + lane)*8);
        #pragma unroll
        for (int kk = 0; kk < 8; ++kk) {
            if (kk < 7) {
                #pragma unroll
                for (int nt = 0; nt < 4; ++nt)
                    if (nt >= j-15 && nt <= j)
                        bfB[nt] = *(const short8*)(B2f + (((size_t)(j*8 + kk+1)*4 + nt)*64 + lane)*8);
            }
            short8 af[2];
            #pragma unroll
            for (int mt = 0; mt < 2; ++mt) {
                int row = 64*mt + 4*li + j;
                int p = (kk*4 + gq) ^ ((row >> 2) & 7);
                af[mt] = *(const short8*)(As + row*512 + p*16);
            }
            __builtin_amdgcn_s_setprio(1);
            #pragma unroll
            for (int mt = 0; mt < 2; ++mt)
                #pragma unroll
                for (int nt = 0; nt < 4; ++nt)
                    if (nt >= j-15 && nt <= j)
                        acc[mt][nt] = __builtin_amdgcn_mfma_f32_16x16x32_bf16(af[mt], bfA[nt], acc[mt][nt], 0, 0, 0);
            __builtin_amdgcn_s_setprio(0);
            #pragma unroll
            for (int nt = 0; nt < 4; ++nt) bfA[nt] = bfB[nt];
        }
    }
    __syncthreads();

    float* red = (float*)As;
    #pragma unroll
    for (int mt = 0; mt < 2; ++mt)
        #pragma unroll
        for (int nt = 0; nt < 4; ++nt) {
            int u = nt*16 + li;
            #pragma unroll
            for (int rr = 0; rr < 4; ++rr) {
                int Pl = 16*mt + gq*4 + rr;
                red[w*2176 + Pl*68 + u] = acc[mt][nt][rr];
            }
        }
    __syncthreads();

    {
        int P = tid >> 4, uq = tid & 15;
        f32x4 s = (f32x4){0.f,0.f,0.f,0.f};
        #pragma unroll
        for (int c = 0; c < 8; ++c)
            s += *(const f32x4*)&red[c*2176 + P*68 + uq*4];
        int ub = (uq & 3)*4;
        f32x4 c2v = { C2[ub], C2[ub+1], C2[ub+2], C2[ub+3] };
        float* ob = out + (size_t)b*TT + (size_t)P0*64;
        *(f32x4*)&ob[P*64 + uq*4] = s + c2v;
    }
}

extern "C" void kernel_launch(void* const* d_in, const int* in_sizes, int n_in,
                              void* d_out, int out_size, void* d_ws, size_t ws_size,
                              hipStream_t stream)
{
    const float* x       = (const float*)d_in[0];
    const float* cw      = (const float*)d_in[1];
    const float* cb      = (const float*)d_in[2];
    const float* cgt     = (const float*)d_in[3];
    const float* cs      = (const float*)d_in[4];
    const float* bng     = (const float*)d_in[5];
    const float* bnb     = (const float*)d_in[6];
    const float* ctw     = (const float*)d_in[7];
    const float* ctb     = (const float*)d_in[8];
    const float* ctg     = (const float*)d_in[9];
    const float* ctscale = (const float*)d_in[10];
    float* out = (float*)d_out;

    char* ws = (char*)d_ws;
    size_t off = 0;
    unsigned short* h    = (unsigned short*)(ws + off); off += (size_t)BB*LL*KK*2;
    float* psum          = (float*)(ws + off);          off += (size_t)KK*NPART*4;
    float* psq           = (float*)(ws + off);          off += (size_t)KK*NPART*4;
    float* W3s           = (float*)(ws + off);          off += (size_t)KK*KK*4;
    float* SWS           = (float*)(ws + off);          off += (size_t)KK*16*4;
    float* C2            = (float*)(ws + off);          off += 64;
    float* cbs           = (float*)(ws + off);          off += 1024;
    float* Wp            = (float*)(ws + off);          off += 9*32*8*4;
    unsigned short* B2f  = (unsigned short*)(ws + off); off += (size_t)NJ*8*4*64*8*2;

    k0s_wp  <<<9, 256, 0, stream>>>(cw, cgt, cs, cb, Wp, cbs);
    k1_conv <<<dim3(NLT, BB), 256, 0, stream>>>(x, cbs, Wp, h, psum, psq);
    k2_bn   <<<KK, 256, 0, stream>>>(psum, psq, bng, bnb, ctw, ctg, ctscale, W3s, SWS);
    k2b_const<<<1, 256, 0, stream>>>(SWS, ctb, ctscale, C2);
    k2c_b2f <<<152, 256, 0, stream>>>(W3s, B2f);
    k3_synth<<<dim3(NPT3, BB), 512, 0, stream>>>(h, B2f, C2, out);
}